// Round 1
// baseline (584.614 us; speedup 1.0000x reference)
//
#include <hip/hip_runtime.h>

#define L_SEQ 1024
#define NB 32
#define NH 8
#define NE 64
#define TOPK 6

__device__ __forceinline__ int padk(int i) { return i + (i >> 4); }

// ---------------- Kernel A: circular cross-correlation ----------------
// corr[n,h,e,l] = sum_t q[n,h,e,t] * k[n,h,e,(t-l) & 1023]
// grid: x = H*16 (h, e-tile of 4), y = N. block = 256 (4 waves, 1 series/wave)
__global__ __launch_bounds__(256) void corr_kernel(
    const float* __restrict__ q, const float* __restrict__ k,
    float* __restrict__ corr_out, float* __restrict__ ws_mean)
{
    __shared__ float q_lds[4][1025];   // +1 pad: staging-write bank spread
    __shared__ float k_lds[4][1089];   // padk layout: stride-16 reads conflict-free

    const int tid = threadIdx.x;
    const int n  = blockIdx.y;
    const int h  = blockIdx.x >> 4;
    const int e0 = (blockIdx.x & 15) << 2;
    const int el = tid & 3;
    const int tq = tid >> 2;

    // stage q,k (4 series) into LDS
    for (int tb = 0; tb < L_SEQ; tb += 64) {
        const int t = tb + tq;
        const size_t base = ((((size_t)n * L_SEQ + t) * NH + h) * NE) + e0 + el;
        q_lds[el][t] = q[base];
        k_lds[el][padk(t)] = k[base];
    }
    __syncthreads();

    const int wave = tid >> 6;
    const int lane = tid & 63;
    const int l0 = lane << 4;          // this lane owns lags l0..l0+15
    const float* __restrict__ qrow = q_lds[wave];
    const float* __restrict__ krow = k_lds[wave];

    float acc[16];
    float w[16];
#pragma unroll
    for (int c = 0; c < 16; ++c) acc[c] = 0.f;
    // preload window so that after the first shift, w[c] = k[(0 - l0 - c) & 1023]
#pragma unroll
    for (int j = 0; j < 15; ++j) {
        const int idx = (-l0 - j - 1) & (L_SEQ - 1);
        w[j] = krow[padk(idx)];
    }
    w[15] = 0.f;

#pragma unroll 1
    for (int tb = 0; tb < L_SEQ; tb += 16) {
#pragma unroll
        for (int tt = 0; tt < 16; ++tt) {
            const int t = tb + tt;
            // shift window (register rotation; unrolled -> copy-propagated)
#pragma unroll
            for (int c = 15; c >= 1; --c) w[c] = w[c - 1];
            const int idx = (t - l0) & (L_SEQ - 1);
            w[0] = krow[padk(idx)];
            const float qv = qrow[t];
#pragma unroll
            for (int c = 0; c < 16; ++c) acc[c] = fmaf(qv, w[c], acc[c]);
        }
    }

    // each wave writes its own q_lds row (only itself ever touched it) -> transpose
#pragma unroll
    for (int c = 0; c < 16; ++c) q_lds[wave][l0 + c] = acc[c];
    __syncthreads();

    // corr_out[n][l][h][e] = corr value; ~coalesced 16B segments
    for (int lb = 0; lb < L_SEQ; lb += 64) {
        const int l = lb + tq;
        corr_out[((((size_t)n * L_SEQ + l) * NH + h) * NE) + e0 + el] = q_lds[el][l];
    }
    // partial sum over (h,e): 4 series summed here, one atomic per l per block
    for (int lb = 0; lb < L_SEQ; lb += 256) {
        const int l = lb + tid;
        const float s = q_lds[0][l] + q_lds[1][l] + q_lds[2][l] + q_lds[3][l];
        atomicAdd(&ws_mean[n * L_SEQ + l], s);
    }
}

// ---------------- Kernel B: top-6 lags + per-n softmax ----------------
__global__ __launch_bounds__(1024) void topk_softmax_kernel(
    const float* __restrict__ ws_mean, int* __restrict__ ws_idx,
    float* __restrict__ ws_w)
{
    __shared__ float val[1024];
    __shared__ float rv[1024];
    __shared__ int   ri[1024];
    __shared__ int   sel[TOPK];
    const int tid = threadIdx.x;

    float s = 0.f;
    for (int n = 0; n < NB; ++n) s += ws_mean[n * L_SEQ + tid];
    val[tid] = s;                       // positive scale: ordering unchanged
    __syncthreads();

    for (int kk = 0; kk < TOPK; ++kk) {
        rv[tid] = val[tid];
        ri[tid] = tid;
        __syncthreads();
        for (int off = 512; off > 0; off >>= 1) {
            if (tid < off) {
                const float a = rv[tid], b = rv[tid + off];
                const int ia = ri[tid], ib = ri[tid + off];
                if (b > a || (b == a && ib < ia)) { rv[tid] = b; ri[tid] = ib; }
            }
            __syncthreads();
        }
        if (tid == 0) { sel[kk] = ri[0]; val[ri[0]] = -1e30f; }
        __syncthreads();
    }
    if (tid < TOPK) ws_idx[tid] = sel[tid];

    if (tid < NB) {   // per-n softmax over the 6 selected lags; scale 1/512 matters
        float wv[TOPK];
        float m = -1e30f;
        for (int kk = 0; kk < TOPK; ++kk) {
            wv[kk] = ws_mean[tid * L_SEQ + sel[kk]] * (1.f / (NH * NE));
            m = fmaxf(m, wv[kk]);
        }
        float sum = 0.f;
        for (int kk = 0; kk < TOPK; ++kk) { wv[kk] = expf(wv[kk] - m); sum += wv[kk]; }
        const float inv = 1.f / sum;
        for (int kk = 0; kk < TOPK; ++kk) ws_w[tid * 8 + kk] = wv[kk] * inv;
    }
}

// ---------------- Kernel C: lag-gather weighted sum of v ----------------
// out[n][l][h][e] = sum_k w[n][k] * v_in[n][(l+idx_k)&1023][h][e]
__global__ __launch_bounds__(256) void gather_kernel(
    const float* __restrict__ v, const int* __restrict__ ws_idx,
    const float* __restrict__ ws_w, float* __restrict__ out)
{
    const int n = blockIdx.y;
    const int idx4 = blockIdx.x * 256 + threadIdx.x;   // 0..131071 per n
    const int l = idx4 >> 7;
    const int r = idx4 & 127;
    const float* wrow = ws_w + n * 8;

    float4 acc = make_float4(0.f, 0.f, 0.f, 0.f);
#pragma unroll
    for (int kk = 0; kk < TOPK; ++kk) {
        const int t = (l + ws_idx[kk]) & (L_SEQ - 1);
        const float4 vv = *reinterpret_cast<const float4*>(
            v + (((size_t)n * L_SEQ + t) * (NH * NE)) + r * 4);
        const float wk = wrow[kk];
        acc.x = fmaf(wk, vv.x, acc.x);
        acc.y = fmaf(wk, vv.y, acc.y);
        acc.z = fmaf(wk, vv.z, acc.z);
        acc.w = fmaf(wk, vv.w, acc.w);
    }
    *reinterpret_cast<float4*>(out + ((size_t)n * L_SEQ + l) * (NH * NE) + r * 4) = acc;
}

extern "C" void kernel_launch(void* const* d_in, const int* in_sizes, int n_in,
                              void* d_out, int out_size, void* d_ws, size_t ws_size,
                              hipStream_t stream)
{
    const float* q = (const float*)d_in[0];
    const float* k = (const float*)d_in[1];
    const float* v = (const float*)d_in[2];
    float* out = (float*)d_out;
    float* corr_out = out + (size_t)NB * L_SEQ * NH * NE;

    float* ws_mean = (float*)d_ws;                              // 32*1024 f32
    int*   ws_idx  = (int*)((char*)d_ws + 131072);              // 6 ints
    float* ws_w    = (float*)((char*)d_ws + 131072 + 256);      // 32*8 f32

    hipMemsetAsync(d_ws, 0, 131072, stream);   // ws is NOT re-poisoned between replays
    corr_kernel<<<dim3(NH * 16, NB), 256, 0, stream>>>(q, k, corr_out, ws_mean);
    topk_softmax_kernel<<<1, 1024, 0, stream>>>(ws_mean, ws_idx, ws_w);
    gather_kernel<<<dim3(512, NB), 256, 0, stream>>>(v, ws_idx, ws_w, out);
}